// Round 19
// baseline (130.489 us; speedup 1.0000x reference)
//
#include <hip/hip_runtime.h>
#include <stdint.h>

#define NCLS    80
#define NA_TOT  8400     // 6400 + 1600 + 400
#define NBATCH  32
#define MAXDET  300
#define SSORT   2048
#define RANKCAP 1536
#define CONFTHR 0.001f
#define TILES_PER_IMG 132   // 100 (L0) + 25 (L1) + 7 (L2, clamped)
#define GKCAP   2056        // per-image key slots (2048 + pad)

// ---------------------------------------------------------------------------
// Bit-exact reconstruction of XLA:CPU f32 exp (Eigen/Cephes pexp, no FMA) and
// logistic = 1/(1+exp(-x)). Validated absmax==0.0 rounds 1-18. DO NOT TOUCH.
// ---------------------------------------------------------------------------
__device__ __forceinline__ float xla_expf(float in) {
  const float exp_hi = 88.3762626647950f;
  const float exp_lo = -88.3762626647949f;
  const float LOG2EF = 1.44269504088896341f;
  const float C1 = 0.693359375f;
  const float C2 = -2.12194440e-4f;
  const float p0 = 1.9875691500E-4f, p1 = 1.3981999507E-3f, p2 = 8.3334519073E-3f;
  const float p3 = 4.1665795894E-2f, p4 = 1.6666665459E-1f, p5 = 5.0000001201E-1f;
  float x = fminf(fmaxf(in, exp_lo), exp_hi);
  float fx = floorf(__fadd_rn(__fmul_rn(x, LOG2EF), 0.5f));
  float tmp = __fmul_rn(C1, fx);
  float z   = __fmul_rn(C2, fx);
  x = __fsub_rn(x, tmp);
  x = __fsub_rn(x, z);
  float y = __fadd_rn(__fmul_rn(x, p0), p1);
  y = __fadd_rn(__fmul_rn(y, x), p2);
  y = __fadd_rn(__fmul_rn(y, x), p3);
  y = __fadd_rn(__fmul_rn(y, x), p4);
  y = __fadd_rn(__fmul_rn(y, x), p5);
  y = __fadd_rn(__fmul_rn(y, __fmul_rn(x, x)), x);
  y = __fadd_rn(1.0f, y);
  int m = (int)fx;
  float s = __uint_as_float((uint32_t)(m + 127) << 23);
  float r = __fmul_rn(y, s);
  return fmaxf(r, in);
}

__device__ __forceinline__ float xla_sigmoid(float v) {
  float e = xla_expf(-v);
  float den = __fadd_rn(1.0f, e);
  return 1.0f / den;
}

__device__ __forceinline__ void gload_lds16(const float* gp, float* lp) {
  __builtin_amdgcn_global_load_lds(
      (const __attribute__((address_space(1))) void*)gp,
      (__attribute__((address_space(3))) void*)lp, 16, 0, 0);
}

// ---------------------------------------------------------------------------
// Kernel 1: decode v4 — per-wave autonomy, barrier-free (r17/r18 best).
// ---------------------------------------------------------------------------
__global__ __launch_bounds__(256) void yolo_decode_kernel(
    const float* __restrict__ f0, const float* __restrict__ f1,
    const float* __restrict__ f2,
    float4* __restrict__ oboxes, float* __restrict__ oconf,
    float* __restrict__ oclsf) {
  __shared__ float sm[4 * 144 * 16];            // 36,864 B -> 4 blocks/CU
  int bx  = blockIdx.x;
  int b   = bx / TILES_PER_IMG;
  int r   = bx - b * TILES_PER_IMG;
  int tid = threadIdx.x;
  int lane = tid & 63;
  int wv   = tid >> 6;

  const float* base; int Alvl, W, a0, lvlbase; float stridef;
  if (r < 100)      { base = f0 + (size_t)b * (144 * 6400); W = 80; Alvl = 6400;
                      a0 = r * 64; stridef = 8.0f; lvlbase = 0; }
  else if (r < 125) { base = f1 + (size_t)b * (144 * 1600); W = 40; Alvl = 1600;
                      a0 = (r - 100) * 64; stridef = 16.0f; lvlbase = 6400; }
  else              { base = f2 + (size_t)b * (144 * 400);  W = 20; Alvl = 400;
                      int aa = (r - 125) * 64; a0 = (aa + 64 <= 400) ? aa : 336;
                      stridef = 32.0f; lvlbase = 8000; }   // clamped overlap: benign

  int a0w = a0 + wv * 16;
  float* Sw = sm + wv * (144 * 16);

  #pragma unroll
  for (int k = 0; k < 9; ++k) {
    int ch = k * 16 + (lane >> 2);
    const float* gp = base + (size_t)ch * Alvl + a0w + (lane & 3) * 4;
    gload_lds16(gp, Sw + k * 256);
  }
  asm volatile("s_waitcnt vmcnt(0)" ::: "memory");
  __builtin_amdgcn_sched_barrier(0);

  int idx = lane & 15;
  int w   = lane >> 4;
  int ai  = a0w + idx;
  float ax = __fadd_rn((float)(ai % W), 0.5f);
  float ay = __fadd_rn((float)(ai / W), 0.5f);

  float d[16];
  float mx = -INFINITY;
  #pragma unroll
  for (int rr = 0; rr < 16; ++rr) {
    d[rr] = Sw[(w * 16 + rr) * 16 + idx];
    mx = fmaxf(mx, d[rr]);
  }
  float e[16]; float ssum = 0.0f;
  #pragma unroll
  for (int rr = 0; rr < 16; ++rr) {
    e[rr] = xla_expf(__fsub_rn(d[rr], mx));
    ssum = __fadd_rn(ssum, e[rr]);
  }
  float acc = 0.0f;
  #pragma unroll
  for (int rr = 0; rr < 16; ++rr) {
    float p = e[rr] / ssum;
    acc = __fadd_rn(acc, __fmul_rn(p, (float)rr));
  }

  float lt0 = __shfl(acc, idx + 0);
  float lt1 = __shfl(acc, idx + 16);
  float lt2 = __shfl(acc, idx + 32);
  float lt3 = __shfl(acc, idx + 48);

  float best = -INFINITY, second = -INFINITY; int bi = 0;
  #pragma unroll 5
  for (int kk = 0; kk < 20; ++kk) {
    int c = 64 + w * 20 + kk;
    float v = Sw[c * 16 + idx];
    if (v > best)        { second = best; best = v; bi = w * 20 + kk; }
    else if (v > second) { second = v; }
  }
  float gb = __shfl(best, idx + 0), gs = __shfl(second, idx + 0);
  int   gi = __shfl(bi,   idx + 0);
  #pragma unroll
  for (int qq = 1; qq < 4; ++qq) {
    float bq = __shfl(best, idx + qq * 16), sq = __shfl(second, idx + qq * 16);
    int   iq = __shfl(bi,   idx + qq * 16);
    if (bq > gb) { gs = fmaxf(gb, sq); gb = bq; gi = iq; }
    else         { gs = fmaxf(gs, bq); }
  }

  float conf = 0.0f; int cls = gi;
  if (__fsub_rn(gb, gs) < 1e-4f || gb > 5.0f) {
    if (w == 0) {
      float bs = -INFINITY; int bj = 0;
      for (int kk = 0; kk < NCLS; ++kk) {
        float v = Sw[(64 + kk) * 16 + idx];
        float s2 = xla_sigmoid(v);
        if (s2 > bs) { bs = s2; bj = kk; }
      }
      conf = bs; cls = bj;
    }
  } else {
    conf = xla_sigmoid(gb);
  }

  if (w == 0) {
    float x1 = __fsub_rn(ax, lt0);
    float y1 = __fsub_rn(ay, lt1);
    float x2 = __fadd_rn(ax, lt2);
    float y2 = __fadd_rn(ay, lt3);
    float cx = __fmul_rn(__fadd_rn(x1, x2), 0.5f);
    float cy = __fmul_rn(__fadd_rn(y1, y2), 0.5f);
    float ww = __fsub_rn(x2, x1);
    float hh = __fsub_rn(y2, y1);
    int t = b * NA_TOT + lvlbase + a0w + idx;
    oboxes[t] = make_float4(__fmul_rn(cx, stridef), __fmul_rn(cy, stridef),
                            __fmul_rn(ww, stridef), __fmul_rn(hh, stridef));
    conf = (conf > CONFTHR) ? conf : 0.0f;
    oconf[t] = conf;
    oclsf[t] = (float)cls;
  }
}

// ---------------------------------------------------------------------------
// Kernel 2a: per-image select (r18-validated verbatim): descent + compact ->
// global keys.
// ---------------------------------------------------------------------------
struct __align__(16) K2Lds {
  unsigned confL[NA_TOT];               // 33600 B
  unsigned hist[16][257];               // 16448 B
  unsigned tot[257];
  unsigned Tarr[257];
};                                      // ~52 KB

__global__ __launch_bounds__(1024) void yolo_select_kernel(
    const float* __restrict__ conf,
    unsigned long long* __restrict__ g_keys, unsigned* __restrict__ g_scnt,
    float* __restrict__ g_rowd, unsigned long long* __restrict__ g_clsMask) {
  __shared__ K2Lds u;
  __shared__ unsigned s_need, s_prefix, s_found, s_B, s_scnt, s_cut, s_done;
  int b    = blockIdx.x;
  int tid  = threadIdx.x;
  int lane = tid & 63;
  int wv   = tid >> 6;
  const unsigned* confu = (const unsigned*)conf + (size_t)b * NA_TOT;
  unsigned long long* gk = g_keys + (size_t)b * GKCAP;

  for (int i = tid; i < NA_TOT; i += 1024) u.confL[i] = confu[i];
  {
    float4 z4 = make_float4(0.f, 0.f, 0.f, 0.f);
    float4* gr = (float4*)(g_rowd + (size_t)b * 1024 * 8);
    for (int k = tid; k < 2048; k += 1024) gr[k] = z4;
  }
  for (int i = tid; i < NCLS * 16; i += 1024)
    g_clsMask[(size_t)b * (NCLS * 16) + i] = 0ull;
  if (tid == 0) { s_need = 1024; s_prefix = 0; s_cut = 0; s_done = 0; s_scnt = 0; }
  __syncthreads();

  for (int lv = 0; lv < 4; ++lv) {
    __syncthreads();
    if (s_done) break;                          // uniform
    for (int i = tid; i < 16 * 257; i += 1024) ((unsigned*)u.hist)[i] = 0;
    if (tid == 0) { s_found = 0; s_B = 0; }
    __syncthreads();
    unsigned pfx = s_prefix;
    for (int it = 0; it < 9; ++it) {
      int i = tid + it * 1024;
      unsigned c = (i < NA_TOT) ? u.confL[i] : 0u;
      bool in; unsigned bin;
      if (lv == 0)      { in = true;                bin = c >> 23; }
      else if (lv == 1) { in = ((c >> 23) == pfx);  bin = (c >> 15) & 0xFF; }
      else if (lv == 2) { in = ((c >> 15) == pfx);  bin = (c >> 7) & 0xFF; }
      else              { in = ((c >> 7)  == pfx);  bin = c & 0x7F; }
      bool act = (c != 0) && in;
      unsigned long long ab = __ballot(act);
      if (ab) {                                 // wave-uniform branch
        int fl = __ffsll(ab) - 1;
        unsigned fbin = __shfl(bin, fl);
        unsigned long long same = __ballot(act && (bin == fbin));
        if (same == ab) {
          if (lane == fl) atomicAdd(&u.hist[wv][fbin], (unsigned)__popcll(ab));
        } else if (act) {
          atomicAdd(&u.hist[wv][bin], 1u);
        }
      }
    }
    __syncthreads();
    if (tid < 256) {
      unsigned s = 0;
      #pragma unroll
      for (int q = 0; q < 16; ++q) s += u.hist[q][tid];
      u.tot[tid] = s;
    }
    __syncthreads();
    if (tid < 64) {
      unsigned carry = 0;
      if (tid == 0) u.Tarr[256] = 0;
      for (int ch = 3; ch >= 0; --ch) {
        int bb = ch * 64 + tid;
        unsigned v = u.tot[bb];
        #pragma unroll
        for (int off = 1; off < 64; off <<= 1) {
          unsigned t2 = __shfl_down(v, off);
          if (tid + off < 64) v += t2;
        }
        u.Tarr[bb] = v + carry;
        carry += __shfl(v, 0);
      }
    }
    __syncthreads();
    unsigned need = s_need;
    if (tid < 256) {
      unsigned h = u.tot[tid];
      if (h > 0 && u.Tarr[tid + 1] < need && u.Tarr[tid + 1] + h >= need) {
        s_B = (unsigned)tid; s_found = 1;
      }
    }
    __syncthreads();
    if (tid == 0) {
      if (!s_found) { s_cut = 1; s_done = 1; }
      else {
        unsigned B = s_B;
        unsigned selcnt = (1024u - need) + u.Tarr[B];
        if (selcnt <= (unsigned)RANKCAP || lv == 3) {
          s_done = 1;
          if (lv == 0)      s_cut = B << 23;
          else if (lv == 1) s_cut = (s_prefix << 23) | (B << 15);
          else if (lv == 2) s_cut = (s_prefix << 15) | (B << 7);
          else              s_cut = (s_prefix << 7)  | B;
        } else {
          s_need   = need - u.Tarr[B + 1];
          s_prefix = (s_prefix << 8) | B;
        }
      }
    }
  }
  __syncthreads();

  unsigned cut = s_cut;
  for (int it = 0; it < 9; ++it) {
    int i = tid + it * 1024;
    unsigned c = (i < NA_TOT) ? u.confL[i] : 0u;
    bool sel = (c != 0 && c >= cut);
    unsigned long long bal = __ballot(sel);
    unsigned base2 = 0;
    if (lane == 0 && bal) base2 = atomicAdd(&s_scnt, (unsigned)__popcll(bal));
    base2 = __shfl(base2, 0);
    if (sel) {
      unsigned p = base2 + (unsigned)__popcll(bal & ((1ull << lane) - 1ull));
      if (p < SSORT)
        gk[p] = ((unsigned long long)c << 32) |
                (unsigned long long)(0xFFFFFFFFu - (unsigned)i);
    }
  }
  __syncthreads();
  if (tid == 0) {
    unsigned sc = s_scnt; if (sc > SSORT) sc = SSORT;
    g_scnt[b] = sc;
    if (sc & 1u) gk[sc] = 0ull;                 // pad for paired reads
  }
}

// ---------------------------------------------------------------------------
// Kernel 2b: rank + scatter, 8 blocks/image, keys staged to own LDS
// (r18-validated verbatim).
// ---------------------------------------------------------------------------
__global__ __launch_bounds__(256) void yolo_rank_kernel(
    const unsigned long long* __restrict__ g_keys,
    const unsigned* __restrict__ g_scnt,
    const float4* __restrict__ boxes, const float* __restrict__ clsf,
    float* __restrict__ g_rowd, unsigned long long* __restrict__ g_clsMask) {
  __shared__ __align__(16) unsigned long long lk[GKCAP];   // 16,448 B
  int bx   = blockIdx.x;
  int b    = bx >> 3;
  int part = bx & 7;
  int tid  = threadIdx.x;
  const unsigned long long* gk = g_keys + (size_t)b * GKCAP;
  unsigned scnt = g_scnt[b];                    // uniform
  unsigned snp  = (scnt + 1u) & ~1u;

  for (unsigned i = tid; i < snp; i += 256) lk[i] = gk[i];   // coalesced
  __syncthreads();

  unsigned e = (unsigned)(part * 256 + tid);
  if (e >= scnt) return;
  unsigned long long mykey = lk[e];
  unsigned r = 0;
  #pragma unroll 4
  for (unsigned j = 0; j < snp; j += 2) {       // LDS b128 broadcast
    ulonglong2 kk = *reinterpret_cast<const ulonglong2*>(&lk[j]);
    r += (kk.x > mykey) ? 1u : 0u;
    r += (kk.y > mykey) ? 1u : 0u;
  }

  if (r < 1024) {                               // == lax.top_k truncation
    unsigned a = 0xFFFFFFFFu - (unsigned)(mykey & 0xFFFFFFFFull);
    float4 cb = boxes[(size_t)b * NA_TOT + a];
    float cls = clsf[(size_t)b * NA_TOT + a];
    float* rowd = g_rowd + (size_t)b * 1024 * 8;
    float4* gr = (float4*)(rowd + (size_t)r * 8);
    gr[0] = cb;
    gr[1] = make_float4(__uint_as_float((unsigned)(mykey >> 32)), cls, 0.f, 0.f);
    atomicOr(&g_clsMask[(size_t)b * (NCLS * 16) + (int)cls * 16 + (r >> 6)],
             1ull << (r & 63));
  }
}

// ---------------------------------------------------------------------------
// Kernel 3a: suppression-row build, 8 blocks/image x 256 threads; thread =
// rank. Exact r12 IoU sequence; rows written LINEAR to global (no swizzle;
// global has no bank conflicts). Invalid ranks write nothing (never read).
// ---------------------------------------------------------------------------
__global__ __launch_bounds__(256) void yolo_rowbuild_kernel(
    const float* __restrict__ g_rowd,
    const unsigned long long* __restrict__ g_clsMask,
    unsigned long long* __restrict__ g_rows) {
  int bx   = blockIdx.x;
  int b    = bx >> 3;
  int part = bx & 7;
  int tid  = threadIdx.x;
  int r    = part * 256 + tid;                  // rank 0..1023
  const float* rowd = g_rowd + (size_t)b * 1024 * 8;
  const float* rd = rowd + (size_t)r * 8;
  float cls = rd[5];
  int c = (int)cls;
  const unsigned long long* cmask = g_clsMask + (size_t)b * (NCLS * 16) + c * 16;
  bool valid = (cmask[r >> 6] >> (r & 63)) & 1ull;
  if (!valid) return;

  float bx0 = rd[0], by0 = rd[1], bw0 = rd[2], bh0 = rd[3];
  float off = __fmul_rn(cls, 7680.0f);
  float hw  = __fmul_rn(bw0, 0.5f), hh = __fmul_rn(bh0, 0.5f);
  float wx1 = __fadd_rn(__fsub_rn(bx0, hw), off);
  float wy1 = __fadd_rn(__fsub_rn(by0, hh), off);
  float wx2 = __fadd_rn(__fadd_rn(bx0, hw), off);
  float wy2 = __fadd_rn(__fadd_rn(by0, hh), off);
  float a1  = __fmul_rn(__fsub_rn(wx2, wx1), __fsub_rn(wy2, wy1));

  unsigned long long row[16];
  #pragma unroll
  for (int q = 0; q < 16; ++q) row[q] = 0ull;

  for (int q = 0; q < 16; ++q) {
    unsigned long long m = cmask[q];
    while (m) {
      int bit = __ffsll(m) - 1;
      m &= m - 1ull;
      int j = q * 64 + bit;
      const float* jd = rowd + (size_t)j * 8;
      float jx = jd[0], jy = jd[1], jw = jd[2], jh = jd[3];
      float jhw = __fmul_rn(jw, 0.5f), jhh = __fmul_rn(jh, 0.5f);
      float jx1 = __fadd_rn(__fsub_rn(jx, jhw), off);
      float jy1 = __fadd_rn(__fsub_rn(jy, jhh), off);
      float jx2 = __fadd_rn(__fadd_rn(jx, jhw), off);
      float jy2 = __fadd_rn(__fadd_rn(jy, jhh), off);
      float ltx = fmaxf(wx1, jx1), lty = fmaxf(wy1, jy1);
      float rbx = fminf(wx2, jx2), rby = fminf(wy2, jy2);
      float iw = fmaxf(__fsub_rn(rbx, ltx), 0.0f);
      float ih = fmaxf(__fsub_rn(rby, lty), 0.0f);
      float inter = __fmul_rn(iw, ih);
      float a2 = __fmul_rn(__fsub_rn(jx2, jx1), __fsub_rn(jy2, jy1));
      float den = __fadd_rn(__fsub_rn(__fadd_rn(a1, a2), inter), 1e-7f);
      float iou = inter / den;
      if (iou > 0.7f)
        row[q] |= (1ull << (j & 63));
    }
  }

  ulonglong2* gro = (ulonglong2*)(g_rows + ((size_t)b * 1024 + r) * 16);
  #pragma unroll
  for (int q = 0; q < 8; ++q)
    gro[q] = make_ulonglong2(row[q * 2], row[q * 2 + 1]);
}

// ---------------------------------------------------------------------------
// Kernel 3b: per-class-parallel walks (rows from global) + parallel popcount
// emit + sticky tail (r12-validated semantics). LDS = am[16] only.
// ---------------------------------------------------------------------------
__global__ __launch_bounds__(1024) void yolo_walk_kernel(
    const float* __restrict__ g_rowd,
    const unsigned long long* __restrict__ g_clsMask,
    const unsigned long long* __restrict__ g_rows,
    float* __restrict__ out) {
  __shared__ unsigned long long am[16];
  __shared__ unsigned s_sticky, s_fill;
  int b   = blockIdx.x;
  int tid = threadIdx.x;
  const unsigned long long* cm = g_clsMask + (size_t)b * (NCLS * 16);
  const unsigned long long* gr = g_rows + (size_t)b * 1024 * 16;
  const float* rowd = g_rowd + (size_t)b * 1024 * 8;

  if (tid < 16) am[tid] = 0ull;
  if (tid == 0) { s_sticky = 0xFFFFFFFFu; s_fill = 0; }
  __syncthreads();

  // ---- per-class-parallel walks (80 threads; register alive masks) ----
  if (tid < NCLS) {
    const unsigned long long* cmask = cm + tid * 16;
    unsigned long long alive[16];
    bool any = false;
    #pragma unroll
    for (int q = 0; q < 16; ++q) { alive[q] = cmask[q]; any |= (alive[q] != 0ull); }
    while (any) {
      int r = -1;
      #pragma unroll
      for (int q = 0; q < 16; ++q)
        if (r < 0 && alive[q]) r = q * 64 + (__ffsll(alive[q]) - 1);
      atomicOr(&am[r >> 6], 1ull << (r & 63));
      const unsigned long long* rw = gr + (size_t)r * 16;
      unsigned long long selfw = rw[r >> 6];
      bool selfbit = (selfw >> (r & 63)) & 1ull;
      if (!selfbit) { atomicMin(&s_sticky, (unsigned)r); break; }  // sticky
      any = false;
      #pragma unroll
      for (int q = 0; q < 16; ++q) {
        alive[q] &= ~rw[q];
        any |= (alive[q] != 0ull);
      }
    }
  }
  __syncthreads();

  // ---- parallel emit: survivor r -> row popc(am below r) ----
  unsigned rs = s_sticky;
  {
    unsigned r = (unsigned)tid;
    bool surv = (am[r >> 6] >> (r & 63)) & 1ull;
    if (surv && r <= rs) {
      unsigned e2 = 0;
      int hi = (int)(r >> 6);
      #pragma unroll
      for (int q = 0; q < 16; ++q) {
        unsigned long long m = am[q];
        if (q < hi)       e2 += (unsigned)__popcll(m);
        else if (q == hi) e2 += (unsigned)__popcll(m & ((1ull << (r & 63)) - 1ull));
      }
      if (e2 < MAXDET) {
        const float* rd = rowd + (size_t)r * 8;
        float* orow = out + (size_t)b * (MAXDET * 6) + (size_t)e2 * 6;
        orow[0] = rd[0];
        orow[1] = rd[1];
        orow[2] = rd[2];
        orow[3] = rd[3];
        orow[4] = rd[4];
        orow[5] = rd[5];
      }
    }
  }
  if (tid == 0) {
    unsigned fill;
    if (rs != 0xFFFFFFFFu) {
      unsigned es = 0;
      int hi = (int)(rs >> 6);
      #pragma unroll
      for (int q = 0; q < 16; ++q) {
        unsigned long long m = am[q];
        if (q < hi)       es += (unsigned)__popcll(m);
        else if (q == hi) es += (unsigned)__popcll(m & ((1ull << (rs & 63)) - 1ull));
      }
      fill = es + 1;
    } else {
      unsigned S = 0;
      #pragma unroll
      for (int q = 0; q < 16; ++q) S += (unsigned)__popcll(am[q]);
      fill = S;
    }
    s_fill = (fill > (unsigned)MAXDET) ? (unsigned)MAXDET : fill;
  }
  __syncthreads();

  // ---- tail fill (sticky row copies, else zeros) ----
  {
    unsigned fill = s_fill;
    bool st = (rs != 0xFFFFFFFFu);
    float* orow = out + (size_t)b * (MAXDET * 6);
    for (int i = (int)fill * 6 + tid; i < MAXDET * 6; i += 1024) {
      float v = 0.0f;
      if (st) v = rowd[(size_t)rs * 8 + (i - (i / 6) * 6)];
      orow[i] = v;
    }
  }
}

extern "C" void kernel_launch(void* const* d_in, const int* in_sizes, int n_in,
                              void* d_out, int out_size, void* d_ws, size_t ws_size,
                              hipStream_t stream) {
  const float* f0 = (const float*)d_in[0];
  const float* f1 = (const float*)d_in[1];
  const float* f2 = (const float*)d_in[2];
  float* out = (float*)d_out;

  char* ws = (char*)d_ws;
  float4* boxes = (float4*)ws;                                       // 4,300,800
  float*  conf  = (float*)(ws + (size_t)NBATCH * NA_TOT * 16);       // 1,075,200
  float*  clsf  = (float*)(ws + (size_t)NBATCH * NA_TOT * 20);       // 1,075,200
  size_t off = (size_t)NBATCH * NA_TOT * 24;                         // 6,451,200
  float*  rowd  = (float*)(ws + off);                         off += 1048576;
  unsigned long long* clsm  = (unsigned long long*)(ws + off); off += 327680;
  unsigned long long* gkeys = (unsigned long long*)(ws + off); off += (size_t)NBATCH * GKCAP * 8;
  unsigned* scnts = (unsigned*)(ws + off);                    off += 4096;
  off = (off + 255) & ~(size_t)255;
  unsigned long long* grows = (unsigned long long*)(ws + off);       // 4,194,304

  yolo_decode_kernel<<<NBATCH * TILES_PER_IMG, 256, 0, stream>>>(
      f0, f1, f2, boxes, conf, clsf);
  yolo_select_kernel<<<NBATCH, 1024, 0, stream>>>(conf, gkeys, scnts,
                                                  rowd, clsm);
  yolo_rank_kernel<<<NBATCH * 8, 256, 0, stream>>>(gkeys, scnts, boxes, clsf,
                                                   rowd, clsm);
  yolo_rowbuild_kernel<<<NBATCH * 8, 256, 0, stream>>>(rowd, clsm, grows);
  yolo_walk_kernel<<<NBATCH, 1024, 0, stream>>>(rowd, clsm, grows, out);
}

// Round 20
// 124.033 us; speedup vs baseline: 1.0521x; 1.0521x over previous
//
#include <hip/hip_runtime.h>
#include <stdint.h>

#define NCLS    80
#define NA_TOT  8400     // 6400 + 1600 + 400
#define NBATCH  32
#define MAXDET  300
#define SSORT   2048
#define RANKCAP 1536
#define CONFTHR 0.001f
#define TILES_PER_IMG 132   // 100 (L0) + 25 (L1) + 7 (L2, clamped)
#define GKCAP   2056        // per-image key slots (2048 + pad)

// ---------------------------------------------------------------------------
// Bit-exact reconstruction of XLA:CPU f32 exp (Eigen/Cephes pexp, no FMA) and
// logistic = 1/(1+exp(-x)). Validated absmax==0.0 rounds 1-19. DO NOT TOUCH.
// ---------------------------------------------------------------------------
__device__ __forceinline__ float xla_expf(float in) {
  const float exp_hi = 88.3762626647950f;
  const float exp_lo = -88.3762626647949f;
  const float LOG2EF = 1.44269504088896341f;
  const float C1 = 0.693359375f;
  const float C2 = -2.12194440e-4f;
  const float p0 = 1.9875691500E-4f, p1 = 1.3981999507E-3f, p2 = 8.3334519073E-3f;
  const float p3 = 4.1665795894E-2f, p4 = 1.6666665459E-1f, p5 = 5.0000001201E-1f;
  float x = fminf(fmaxf(in, exp_lo), exp_hi);
  float fx = floorf(__fadd_rn(__fmul_rn(x, LOG2EF), 0.5f));
  float tmp = __fmul_rn(C1, fx);
  float z   = __fmul_rn(C2, fx);
  x = __fsub_rn(x, tmp);
  x = __fsub_rn(x, z);
  float y = __fadd_rn(__fmul_rn(x, p0), p1);
  y = __fadd_rn(__fmul_rn(y, x), p2);
  y = __fadd_rn(__fmul_rn(y, x), p3);
  y = __fadd_rn(__fmul_rn(y, x), p4);
  y = __fadd_rn(__fmul_rn(y, x), p5);
  y = __fadd_rn(__fmul_rn(y, __fmul_rn(x, x)), x);
  y = __fadd_rn(1.0f, y);
  int m = (int)fx;
  float s = __uint_as_float((uint32_t)(m + 127) << 23);
  float r = __fmul_rn(y, s);
  return fmaxf(r, in);
}

__device__ __forceinline__ float xla_sigmoid(float v) {
  float e = xla_expf(-v);
  float den = __fadd_rn(1.0f, e);
  return 1.0f / den;
}

__device__ __forceinline__ void gload_lds16(const float* gp, float* lp) {
  __builtin_amdgcn_global_load_lds(
      (const __attribute__((address_space(1))) void*)gp,
      (__attribute__((address_space(3))) void*)lp, 16, 0, 0);
}

// ---------------------------------------------------------------------------
// Kernel 1: decode v4 — per-wave autonomy, barrier-free (r17/r18 best).
// ---------------------------------------------------------------------------
__global__ __launch_bounds__(256) void yolo_decode_kernel(
    const float* __restrict__ f0, const float* __restrict__ f1,
    const float* __restrict__ f2,
    float4* __restrict__ oboxes, float* __restrict__ oconf,
    float* __restrict__ oclsf) {
  __shared__ float sm[4 * 144 * 16];            // 36,864 B -> 4 blocks/CU
  int bx  = blockIdx.x;
  int b   = bx / TILES_PER_IMG;
  int r   = bx - b * TILES_PER_IMG;
  int tid = threadIdx.x;
  int lane = tid & 63;
  int wv   = tid >> 6;

  const float* base; int Alvl, W, a0, lvlbase; float stridef;
  if (r < 100)      { base = f0 + (size_t)b * (144 * 6400); W = 80; Alvl = 6400;
                      a0 = r * 64; stridef = 8.0f; lvlbase = 0; }
  else if (r < 125) { base = f1 + (size_t)b * (144 * 1600); W = 40; Alvl = 1600;
                      a0 = (r - 100) * 64; stridef = 16.0f; lvlbase = 6400; }
  else              { base = f2 + (size_t)b * (144 * 400);  W = 20; Alvl = 400;
                      int aa = (r - 125) * 64; a0 = (aa + 64 <= 400) ? aa : 336;
                      stridef = 32.0f; lvlbase = 8000; }   // clamped overlap: benign

  int a0w = a0 + wv * 16;
  float* Sw = sm + wv * (144 * 16);

  #pragma unroll
  for (int k = 0; k < 9; ++k) {
    int ch = k * 16 + (lane >> 2);
    const float* gp = base + (size_t)ch * Alvl + a0w + (lane & 3) * 4;
    gload_lds16(gp, Sw + k * 256);
  }
  asm volatile("s_waitcnt vmcnt(0)" ::: "memory");
  __builtin_amdgcn_sched_barrier(0);

  int idx = lane & 15;
  int w   = lane >> 4;
  int ai  = a0w + idx;
  float ax = __fadd_rn((float)(ai % W), 0.5f);
  float ay = __fadd_rn((float)(ai / W), 0.5f);

  float d[16];
  float mx = -INFINITY;
  #pragma unroll
  for (int rr = 0; rr < 16; ++rr) {
    d[rr] = Sw[(w * 16 + rr) * 16 + idx];
    mx = fmaxf(mx, d[rr]);
  }
  float e[16]; float ssum = 0.0f;
  #pragma unroll
  for (int rr = 0; rr < 16; ++rr) {
    e[rr] = xla_expf(__fsub_rn(d[rr], mx));
    ssum = __fadd_rn(ssum, e[rr]);
  }
  float acc = 0.0f;
  #pragma unroll
  for (int rr = 0; rr < 16; ++rr) {
    float p = e[rr] / ssum;
    acc = __fadd_rn(acc, __fmul_rn(p, (float)rr));
  }

  float lt0 = __shfl(acc, idx + 0);
  float lt1 = __shfl(acc, idx + 16);
  float lt2 = __shfl(acc, idx + 32);
  float lt3 = __shfl(acc, idx + 48);

  float best = -INFINITY, second = -INFINITY; int bi = 0;
  #pragma unroll 5
  for (int kk = 0; kk < 20; ++kk) {
    int c = 64 + w * 20 + kk;
    float v = Sw[c * 16 + idx];
    if (v > best)        { second = best; best = v; bi = w * 20 + kk; }
    else if (v > second) { second = v; }
  }
  float gb = __shfl(best, idx + 0), gs = __shfl(second, idx + 0);
  int   gi = __shfl(bi,   idx + 0);
  #pragma unroll
  for (int qq = 1; qq < 4; ++qq) {
    float bq = __shfl(best, idx + qq * 16), sq = __shfl(second, idx + qq * 16);
    int   iq = __shfl(bi,   idx + qq * 16);
    if (bq > gb) { gs = fmaxf(gb, sq); gb = bq; gi = iq; }
    else         { gs = fmaxf(gs, bq); }
  }

  float conf = 0.0f; int cls = gi;
  if (__fsub_rn(gb, gs) < 1e-4f || gb > 5.0f) {
    if (w == 0) {
      float bs = -INFINITY; int bj = 0;
      for (int kk = 0; kk < NCLS; ++kk) {
        float v = Sw[(64 + kk) * 16 + idx];
        float s2 = xla_sigmoid(v);
        if (s2 > bs) { bs = s2; bj = kk; }
      }
      conf = bs; cls = bj;
    }
  } else {
    conf = xla_sigmoid(gb);
  }

  if (w == 0) {
    float x1 = __fsub_rn(ax, lt0);
    float y1 = __fsub_rn(ay, lt1);
    float x2 = __fadd_rn(ax, lt2);
    float y2 = __fadd_rn(ay, lt3);
    float cx = __fmul_rn(__fadd_rn(x1, x2), 0.5f);
    float cy = __fmul_rn(__fadd_rn(y1, y2), 0.5f);
    float ww = __fsub_rn(x2, x1);
    float hh = __fsub_rn(y2, y1);
    int t = b * NA_TOT + lvlbase + a0w + idx;
    oboxes[t] = make_float4(__fmul_rn(cx, stridef), __fmul_rn(cy, stridef),
                            __fmul_rn(ww, stridef), __fmul_rn(hh, stridef));
    conf = (conf > CONFTHR) ? conf : 0.0f;
    oconf[t] = conf;
    oclsf[t] = (float)cls;
  }
}

// ---------------------------------------------------------------------------
// Kernel 2a: per-image select (r18-validated verbatim): descent + compact ->
// global keys.
// ---------------------------------------------------------------------------
struct __align__(16) K2Lds {
  unsigned confL[NA_TOT];               // 33600 B
  unsigned hist[16][257];               // 16448 B
  unsigned tot[257];
  unsigned Tarr[257];
};                                      // ~52 KB

__global__ __launch_bounds__(1024) void yolo_select_kernel(
    const float* __restrict__ conf,
    unsigned long long* __restrict__ g_keys, unsigned* __restrict__ g_scnt,
    float* __restrict__ g_rowd, unsigned long long* __restrict__ g_clsMask) {
  __shared__ K2Lds u;
  __shared__ unsigned s_need, s_prefix, s_found, s_B, s_scnt, s_cut, s_done;
  int b    = blockIdx.x;
  int tid  = threadIdx.x;
  int lane = tid & 63;
  int wv   = tid >> 6;
  const unsigned* confu = (const unsigned*)conf + (size_t)b * NA_TOT;
  unsigned long long* gk = g_keys + (size_t)b * GKCAP;

  for (int i = tid; i < NA_TOT; i += 1024) u.confL[i] = confu[i];
  {
    float4 z4 = make_float4(0.f, 0.f, 0.f, 0.f);
    float4* gr = (float4*)(g_rowd + (size_t)b * 1024 * 8);
    for (int k = tid; k < 2048; k += 1024) gr[k] = z4;
  }
  for (int i = tid; i < NCLS * 16; i += 1024)
    g_clsMask[(size_t)b * (NCLS * 16) + i] = 0ull;
  if (tid == 0) { s_need = 1024; s_prefix = 0; s_cut = 0; s_done = 0; s_scnt = 0; }
  __syncthreads();

  for (int lv = 0; lv < 4; ++lv) {
    __syncthreads();
    if (s_done) break;                          // uniform
    for (int i = tid; i < 16 * 257; i += 1024) ((unsigned*)u.hist)[i] = 0;
    if (tid == 0) { s_found = 0; s_B = 0; }
    __syncthreads();
    unsigned pfx = s_prefix;
    for (int it = 0; it < 9; ++it) {
      int i = tid + it * 1024;
      unsigned c = (i < NA_TOT) ? u.confL[i] : 0u;
      bool in; unsigned bin;
      if (lv == 0)      { in = true;                bin = c >> 23; }
      else if (lv == 1) { in = ((c >> 23) == pfx);  bin = (c >> 15) & 0xFF; }
      else if (lv == 2) { in = ((c >> 15) == pfx);  bin = (c >> 7) & 0xFF; }
      else              { in = ((c >> 7)  == pfx);  bin = c & 0x7F; }
      bool act = (c != 0) && in;
      unsigned long long ab = __ballot(act);
      if (ab) {                                 // wave-uniform branch
        int fl = __ffsll(ab) - 1;
        unsigned fbin = __shfl(bin, fl);
        unsigned long long same = __ballot(act && (bin == fbin));
        if (same == ab) {
          if (lane == fl) atomicAdd(&u.hist[wv][fbin], (unsigned)__popcll(ab));
        } else if (act) {
          atomicAdd(&u.hist[wv][bin], 1u);
        }
      }
    }
    __syncthreads();
    if (tid < 256) {
      unsigned s = 0;
      #pragma unroll
      for (int q = 0; q < 16; ++q) s += u.hist[q][tid];
      u.tot[tid] = s;
    }
    __syncthreads();
    if (tid < 64) {
      unsigned carry = 0;
      if (tid == 0) u.Tarr[256] = 0;
      for (int ch = 3; ch >= 0; --ch) {
        int bb = ch * 64 + tid;
        unsigned v = u.tot[bb];
        #pragma unroll
        for (int off = 1; off < 64; off <<= 1) {
          unsigned t2 = __shfl_down(v, off);
          if (tid + off < 64) v += t2;
        }
        u.Tarr[bb] = v + carry;
        carry += __shfl(v, 0);
      }
    }
    __syncthreads();
    unsigned need = s_need;
    if (tid < 256) {
      unsigned h = u.tot[tid];
      if (h > 0 && u.Tarr[tid + 1] < need && u.Tarr[tid + 1] + h >= need) {
        s_B = (unsigned)tid; s_found = 1;
      }
    }
    __syncthreads();
    if (tid == 0) {
      if (!s_found) { s_cut = 1; s_done = 1; }
      else {
        unsigned B = s_B;
        unsigned selcnt = (1024u - need) + u.Tarr[B];
        if (selcnt <= (unsigned)RANKCAP || lv == 3) {
          s_done = 1;
          if (lv == 0)      s_cut = B << 23;
          else if (lv == 1) s_cut = (s_prefix << 23) | (B << 15);
          else if (lv == 2) s_cut = (s_prefix << 15) | (B << 7);
          else              s_cut = (s_prefix << 7)  | B;
        } else {
          s_need   = need - u.Tarr[B + 1];
          s_prefix = (s_prefix << 8) | B;
        }
      }
    }
  }
  __syncthreads();

  unsigned cut = s_cut;
  for (int it = 0; it < 9; ++it) {
    int i = tid + it * 1024;
    unsigned c = (i < NA_TOT) ? u.confL[i] : 0u;
    bool sel = (c != 0 && c >= cut);
    unsigned long long bal = __ballot(sel);
    unsigned base2 = 0;
    if (lane == 0 && bal) base2 = atomicAdd(&s_scnt, (unsigned)__popcll(bal));
    base2 = __shfl(base2, 0);
    if (sel) {
      unsigned p = base2 + (unsigned)__popcll(bal & ((1ull << lane) - 1ull));
      if (p < SSORT)
        gk[p] = ((unsigned long long)c << 32) |
                (unsigned long long)(0xFFFFFFFFu - (unsigned)i);
    }
  }
  __syncthreads();
  if (tid == 0) {
    unsigned sc = s_scnt; if (sc > SSORT) sc = SSORT;
    g_scnt[b] = sc;
    if (sc & 1u) gk[sc] = 0ull;                 // pad for paired reads
  }
}

// ---------------------------------------------------------------------------
// Kernel 2b: rank + scatter, 8 blocks/image, keys staged to own LDS
// (r18-validated verbatim).
// ---------------------------------------------------------------------------
__global__ __launch_bounds__(256) void yolo_rank_kernel(
    const unsigned long long* __restrict__ g_keys,
    const unsigned* __restrict__ g_scnt,
    const float4* __restrict__ boxes, const float* __restrict__ clsf,
    float* __restrict__ g_rowd, unsigned long long* __restrict__ g_clsMask) {
  __shared__ __align__(16) unsigned long long lk[GKCAP];   // 16,448 B
  int bx   = blockIdx.x;
  int b    = bx >> 3;
  int part = bx & 7;
  int tid  = threadIdx.x;
  const unsigned long long* gk = g_keys + (size_t)b * GKCAP;
  unsigned scnt = g_scnt[b];                    // uniform
  unsigned snp  = (scnt + 1u) & ~1u;

  for (unsigned i = tid; i < snp; i += 256) lk[i] = gk[i];   // coalesced
  __syncthreads();

  unsigned e = (unsigned)(part * 256 + tid);
  if (e >= scnt) return;
  unsigned long long mykey = lk[e];
  unsigned r = 0;
  #pragma unroll 4
  for (unsigned j = 0; j < snp; j += 2) {       // LDS b128 broadcast
    ulonglong2 kk = *reinterpret_cast<const ulonglong2*>(&lk[j]);
    r += (kk.x > mykey) ? 1u : 0u;
    r += (kk.y > mykey) ? 1u : 0u;
  }

  if (r < 1024) {                               // == lax.top_k truncation
    unsigned a = 0xFFFFFFFFu - (unsigned)(mykey & 0xFFFFFFFFull);
    float4 cb = boxes[(size_t)b * NA_TOT + a];
    float cls = clsf[(size_t)b * NA_TOT + a];
    float* rowd = g_rowd + (size_t)b * 1024 * 8;
    float4* gr = (float4*)(rowd + (size_t)r * 8);
    gr[0] = cb;
    gr[1] = make_float4(__uint_as_float((unsigned)(mykey >> 32)), cls, 0.f, 0.f);
    atomicOr(&g_clsMask[(size_t)b * (NCLS * 16) + (int)cls * 16 + (r >> 6)],
             1ull << (r & 63));
  }
}

// ---------------------------------------------------------------------------
// Kernel 3: per-image NMS (r12/r18-validated verbatim): parallel row build +
// per-class-parallel walks + parallel popcount emit + sticky tail.
// ---------------------------------------------------------------------------
struct K3Lds {
  unsigned long long rows[1024][16];    // 131072 B, col-swizzled: phys = q^(tid&15)
  float    rowdata[1024][6];            //  24576 B
  unsigned long long am[16];            //    128 B
};                                      // ~155.8 KB

__global__ __launch_bounds__(1024) void yolo_nms_kernel(
    const float* __restrict__ g_rowd,
    const unsigned long long* __restrict__ g_clsMask,
    float* __restrict__ out) {
  __shared__ K3Lds u;
  __shared__ unsigned s_sticky, s_fill;
  int b    = blockIdx.x;
  int tid  = threadIdx.x;
  const unsigned long long* cm = g_clsMask + (size_t)b * (NCLS * 16);

  {
    const float4* gr = (const float4*)(g_rowd + ((size_t)b * 1024 + tid) * 8);
    float4 v0 = gr[0];
    float4 v1 = gr[1];
    u.rowdata[tid][0] = v0.x; u.rowdata[tid][1] = v0.y;
    u.rowdata[tid][2] = v0.z; u.rowdata[tid][3] = v0.w;
    u.rowdata[tid][4] = v1.x; u.rowdata[tid][5] = v1.y;
  }
  {
    unsigned long long* flat = &u.rows[0][0];
    for (int k = tid; k < 1024 * 16; k += 1024) flat[k] = 0ull;
  }
  if (tid < 16) u.am[tid] = 0ull;
  if (tid == 0) { s_sticky = 0xFFFFFFFFu; s_fill = 0; }
  __syncthreads();

  // ---- build suppression-bit rows (same-class pairs; exact IoU sequence) ----
  {
    float cls = u.rowdata[tid][5];
    int c = (int)cls;
    const unsigned long long* cmask = cm + c * 16;
    bool valid = (cmask[tid >> 6] >> (tid & 63)) & 1ull;
    if (valid) {
      float bx0 = u.rowdata[tid][0], by0 = u.rowdata[tid][1];
      float bw0 = u.rowdata[tid][2], bh0 = u.rowdata[tid][3];
      float off = __fmul_rn(cls, 7680.0f);
      float hw  = __fmul_rn(bw0, 0.5f), hh = __fmul_rn(bh0, 0.5f);
      float wx1 = __fadd_rn(__fsub_rn(bx0, hw), off);
      float wy1 = __fadd_rn(__fsub_rn(by0, hh), off);
      float wx2 = __fadd_rn(__fadd_rn(bx0, hw), off);
      float wy2 = __fadd_rn(__fadd_rn(by0, hh), off);
      float a1  = __fmul_rn(__fsub_rn(wx2, wx1), __fsub_rn(wy2, wy1));
      int sw = tid & 15;
      for (int q = 0; q < 16; ++q) {
        unsigned long long m = cmask[q];
        while (m) {
          int bit = __ffsll(m) - 1;
          m &= m - 1ull;
          int j = q * 64 + bit;
          float jx = u.rowdata[j][0], jy = u.rowdata[j][1];
          float jw = u.rowdata[j][2], jh = u.rowdata[j][3];
          float jhw = __fmul_rn(jw, 0.5f), jhh = __fmul_rn(jh, 0.5f);
          float jx1 = __fadd_rn(__fsub_rn(jx, jhw), off);
          float jy1 = __fadd_rn(__fsub_rn(jy, jhh), off);
          float jx2 = __fadd_rn(__fadd_rn(jx, jhw), off);
          float jy2 = __fadd_rn(__fadd_rn(jy, jhh), off);
          float ltx = fmaxf(wx1, jx1), lty = fmaxf(wy1, jy1);
          float rbx = fminf(wx2, jx2), rby = fminf(wy2, jy2);
          float iw = fmaxf(__fsub_rn(rbx, ltx), 0.0f);
          float ih = fmaxf(__fsub_rn(rby, lty), 0.0f);
          float inter = __fmul_rn(iw, ih);
          float a2 = __fmul_rn(__fsub_rn(jx2, jx1), __fsub_rn(jy2, jy1));
          float den = __fadd_rn(__fsub_rn(__fadd_rn(a1, a2), inter), 1e-7f);
          float iou = inter / den;
          if (iou > 0.7f)
            u.rows[tid][(j >> 6) ^ sw] |= (1ull << (j & 63));
        }
      }
    }
  }
  __syncthreads();

  // ---- per-class-parallel walks (80 threads; register alive masks) ----
  if (tid < NCLS) {
    const unsigned long long* cmask = cm + tid * 16;
    unsigned long long alive[16];
    bool any = false;
    #pragma unroll
    for (int q = 0; q < 16; ++q) { alive[q] = cmask[q]; any |= (alive[q] != 0ull); }
    while (any) {
      int r = -1;
      #pragma unroll
      for (int q = 0; q < 16; ++q)
        if (r < 0 && alive[q]) r = q * 64 + (__ffsll(alive[q]) - 1);
      atomicOr(&u.am[r >> 6], 1ull << (r & 63));
      int sw = r & 15;
      unsigned long long selfw = u.rows[r][(r >> 6) ^ sw];
      bool selfbit = (selfw >> (r & 63)) & 1ull;
      if (!selfbit) { atomicMin(&s_sticky, (unsigned)r); break; }  // sticky
      any = false;
      #pragma unroll
      for (int q = 0; q < 16; ++q) {
        alive[q] &= ~u.rows[r][q ^ sw];
        any |= (alive[q] != 0ull);
      }
    }
  }
  __syncthreads();

  // ---- parallel emit: survivor r -> row popc(am below r) ----
  unsigned rs = s_sticky;
  {
    unsigned r = (unsigned)tid;
    bool surv = (u.am[r >> 6] >> (r & 63)) & 1ull;
    if (surv && r <= rs) {
      unsigned e2 = 0;
      int hi = (int)(r >> 6);
      #pragma unroll
      for (int q = 0; q < 16; ++q) {
        unsigned long long m = u.am[q];
        if (q < hi)       e2 += (unsigned)__popcll(m);
        else if (q == hi) e2 += (unsigned)__popcll(m & ((1ull << (r & 63)) - 1ull));
      }
      if (e2 < MAXDET) {
        float* orow = out + (size_t)b * (MAXDET * 6) + (size_t)e2 * 6;
        orow[0] = u.rowdata[r][0];
        orow[1] = u.rowdata[r][1];
        orow[2] = u.rowdata[r][2];
        orow[3] = u.rowdata[r][3];
        orow[4] = u.rowdata[r][4];
        orow[5] = u.rowdata[r][5];
      }
    }
  }
  if (tid == 0) {
    unsigned fill;
    if (rs != 0xFFFFFFFFu) {
      unsigned es = 0;
      int hi = (int)(rs >> 6);
      #pragma unroll
      for (int q = 0; q < 16; ++q) {
        unsigned long long m = u.am[q];
        if (q < hi)       es += (unsigned)__popcll(m);
        else if (q == hi) es += (unsigned)__popcll(m & ((1ull << (rs & 63)) - 1ull));
      }
      fill = es + 1;
    } else {
      unsigned S = 0;
      #pragma unroll
      for (int q = 0; q < 16; ++q) S += (unsigned)__popcll(u.am[q]);
      fill = S;
    }
    s_fill = (fill > (unsigned)MAXDET) ? (unsigned)MAXDET : fill;
  }
  __syncthreads();

  {
    unsigned fill = s_fill;
    bool st = (rs != 0xFFFFFFFFu);
    float* orow = out + (size_t)b * (MAXDET * 6);
    for (int i = (int)fill * 6 + tid; i < MAXDET * 6; i += 1024) {
      float v = 0.0f;
      if (st) v = u.rowdata[rs][i - (i / 6) * 6];
      orow[i] = v;
    }
  }
}

extern "C" void kernel_launch(void* const* d_in, const int* in_sizes, int n_in,
                              void* d_out, int out_size, void* d_ws, size_t ws_size,
                              hipStream_t stream) {
  const float* f0 = (const float*)d_in[0];
  const float* f1 = (const float*)d_in[1];
  const float* f2 = (const float*)d_in[2];
  float* out = (float*)d_out;

  char* ws = (char*)d_ws;
  float4* boxes = (float4*)ws;                                       // 4,300,800
  float*  conf  = (float*)(ws + (size_t)NBATCH * NA_TOT * 16);       // 1,075,200
  float*  clsf  = (float*)(ws + (size_t)NBATCH * NA_TOT * 20);       // 1,075,200
  size_t off = (size_t)NBATCH * NA_TOT * 24;                         // 6,451,200
  float*  rowd  = (float*)(ws + off);                         off += 1048576;
  unsigned long long* clsm  = (unsigned long long*)(ws + off); off += 327680;
  unsigned long long* gkeys = (unsigned long long*)(ws + off); off += (size_t)NBATCH * GKCAP * 8;
  unsigned* scnts = (unsigned*)(ws + off);

  yolo_decode_kernel<<<NBATCH * TILES_PER_IMG, 256, 0, stream>>>(
      f0, f1, f2, boxes, conf, clsf);
  yolo_select_kernel<<<NBATCH, 1024, 0, stream>>>(conf, gkeys, scnts,
                                                  rowd, clsm);
  yolo_rank_kernel<<<NBATCH * 8, 256, 0, stream>>>(gkeys, scnts, boxes, clsf,
                                                   rowd, clsm);
  yolo_nms_kernel<<<NBATCH, 1024, 0, stream>>>(rowd, clsm, out);
}

// Round 21
// 120.986 us; speedup vs baseline: 1.0785x; 1.0252x over previous
//
#include <hip/hip_runtime.h>
#include <stdint.h>

#define NCLS    80
#define NA_TOT  8400     // 6400 + 1600 + 400
#define NBATCH  32
#define MAXDET  300
#define SSORT   2048
#define RANKCAP 1536
#define CONFTHR 0.001f
#define TILES_PER_IMG 132   // 100 (L0) + 25 (L1) + 7 (L2, clamped)
#define GKCAP   2056        // per-image key slots (2048 + pad)

// ---------------------------------------------------------------------------
// Bit-exact reconstruction of XLA:CPU f32 exp (Eigen/Cephes pexp, no FMA) and
// logistic = 1/(1+exp(-x)). Validated absmax==0.0 rounds 1-20. DO NOT TOUCH.
// ---------------------------------------------------------------------------
__device__ __forceinline__ float xla_expf(float in) {
  const float exp_hi = 88.3762626647950f;
  const float exp_lo = -88.3762626647949f;
  const float LOG2EF = 1.44269504088896341f;
  const float C1 = 0.693359375f;
  const float C2 = -2.12194440e-4f;
  const float p0 = 1.9875691500E-4f, p1 = 1.3981999507E-3f, p2 = 8.3334519073E-3f;
  const float p3 = 4.1665795894E-2f, p4 = 1.6666665459E-1f, p5 = 5.0000001201E-1f;
  float x = fminf(fmaxf(in, exp_lo), exp_hi);
  float fx = floorf(__fadd_rn(__fmul_rn(x, LOG2EF), 0.5f));
  float tmp = __fmul_rn(C1, fx);
  float z   = __fmul_rn(C2, fx);
  x = __fsub_rn(x, tmp);
  x = __fsub_rn(x, z);
  float y = __fadd_rn(__fmul_rn(x, p0), p1);
  y = __fadd_rn(__fmul_rn(y, x), p2);
  y = __fadd_rn(__fmul_rn(y, x), p3);
  y = __fadd_rn(__fmul_rn(y, x), p4);
  y = __fadd_rn(__fmul_rn(y, x), p5);
  y = __fadd_rn(__fmul_rn(y, __fmul_rn(x, x)), x);
  y = __fadd_rn(1.0f, y);
  int m = (int)fx;
  float s = __uint_as_float((uint32_t)(m + 127) << 23);
  float r = __fmul_rn(y, s);
  return fmaxf(r, in);
}

__device__ __forceinline__ float xla_sigmoid(float v) {
  float e = xla_expf(-v);
  float den = __fadd_rn(1.0f, e);
  return 1.0f / den;
}

__device__ __forceinline__ void gload_lds16(const float* gp, float* lp) {
  __builtin_amdgcn_global_load_lds(
      (const __attribute__((address_space(1))) void*)gp,
      (__attribute__((address_space(3))) void*)lp, 16, 0, 0);
}

// ---------------------------------------------------------------------------
// Kernel 1: decode v5 — per-wave autonomy + COUNTED vmcnt split (T4):
// issue all 9 chunks (0-3 = DFL ch 0-63, 4-8 = class ch 64-143), wait
// vmcnt(5) -> DFL chunks landed (FIFO), compute DFL while class chunks
// remain in flight, then vmcnt(0) -> class scan. Arithmetic verbatim r17-r20.
// ---------------------------------------------------------------------------
__global__ __launch_bounds__(256) void yolo_decode_kernel(
    const float* __restrict__ f0, const float* __restrict__ f1,
    const float* __restrict__ f2,
    float4* __restrict__ oboxes, float* __restrict__ oconf,
    float* __restrict__ oclsf) {
  __shared__ float sm[4 * 144 * 16];            // 36,864 B -> 4 blocks/CU
  int bx  = blockIdx.x;
  int b   = bx / TILES_PER_IMG;
  int r   = bx - b * TILES_PER_IMG;
  int tid = threadIdx.x;
  int lane = tid & 63;
  int wv   = tid >> 6;

  const float* base; int Alvl, W, a0, lvlbase; float stridef;
  if (r < 100)      { base = f0 + (size_t)b * (144 * 6400); W = 80; Alvl = 6400;
                      a0 = r * 64; stridef = 8.0f; lvlbase = 0; }
  else if (r < 125) { base = f1 + (size_t)b * (144 * 1600); W = 40; Alvl = 1600;
                      a0 = (r - 100) * 64; stridef = 16.0f; lvlbase = 6400; }
  else              { base = f2 + (size_t)b * (144 * 400);  W = 20; Alvl = 400;
                      int aa = (r - 125) * 64; a0 = (aa + 64 <= 400) ? aa : 336;
                      stridef = 32.0f; lvlbase = 8000; }   // clamped overlap: benign

  int a0w = a0 + wv * 16;
  float* Sw = sm + wv * (144 * 16);

  // ---- issue all 9 chunks in order (0-3 DFL, 4-8 class) ----
  #pragma unroll
  for (int k = 0; k < 9; ++k) {
    int ch = k * 16 + (lane >> 2);
    const float* gp = base + (size_t)ch * Alvl + a0w + (lane & 3) * 4;
    gload_lds16(gp, Sw + k * 256);
  }
  // ---- T4 counted wait: chunks 0-3 (DFL) landed; 4-8 still in flight ----
  asm volatile("s_waitcnt vmcnt(5)" ::: "memory");
  __builtin_amdgcn_sched_barrier(0);

  int idx = lane & 15;
  int w   = lane >> 4;
  int ai  = a0w + idx;
  float ax = __fadd_rn((float)(ai % W), 0.5f);
  float ay = __fadd_rn((float)(ai / W), 0.5f);

  // ---- DFL side w (verbatim sequence; uses only chunks 0-3) ----
  float d[16];
  float mx = -INFINITY;
  #pragma unroll
  for (int rr = 0; rr < 16; ++rr) {
    d[rr] = Sw[(w * 16 + rr) * 16 + idx];
    mx = fmaxf(mx, d[rr]);
  }
  float e[16]; float ssum = 0.0f;
  #pragma unroll
  for (int rr = 0; rr < 16; ++rr) {
    e[rr] = xla_expf(__fsub_rn(d[rr], mx));
    ssum = __fadd_rn(ssum, e[rr]);
  }
  float acc = 0.0f;
  #pragma unroll
  for (int rr = 0; rr < 16; ++rr) {
    float p = e[rr] / ssum;
    acc = __fadd_rn(acc, __fmul_rn(p, (float)rr));
  }

  float lt0 = __shfl(acc, idx + 0);
  float lt1 = __shfl(acc, idx + 16);
  float lt2 = __shfl(acc, idx + 32);
  float lt3 = __shfl(acc, idx + 48);

  // ---- class chunks now needed: drain remaining loads ----
  asm volatile("s_waitcnt vmcnt(0)" ::: "memory");
  __builtin_amdgcn_sched_barrier(0);

  // ---- class top-2, 20 classes per worker (ascending, strict >) ----
  float best = -INFINITY, second = -INFINITY; int bi = 0;
  #pragma unroll 5
  for (int kk = 0; kk < 20; ++kk) {
    int c = 64 + w * 20 + kk;
    float v = Sw[c * 16 + idx];
    if (v > best)        { second = best; best = v; bi = w * 20 + kk; }
    else if (v > second) { second = v; }
  }
  float gb = __shfl(best, idx + 0), gs = __shfl(second, idx + 0);
  int   gi = __shfl(bi,   idx + 0);
  #pragma unroll
  for (int qq = 1; qq < 4; ++qq) {
    float bq = __shfl(best, idx + qq * 16), sq = __shfl(second, idx + qq * 16);
    int   iq = __shfl(bi,   idx + qq * 16);
    if (bq > gb) { gs = fmaxf(gb, sq); gb = bq; gi = iq; }
    else         { gs = fmaxf(gs, bq); }
  }

  float conf = 0.0f; int cls = gi;
  if (__fsub_rn(gb, gs) < 1e-4f || gb > 5.0f) {
    // exact slow path (rare): identical to validated r1 80-sigmoid scan
    if (w == 0) {
      float bs = -INFINITY; int bj = 0;
      for (int kk = 0; kk < NCLS; ++kk) {
        float v = Sw[(64 + kk) * 16 + idx];
        float s2 = xla_sigmoid(v);
        if (s2 > bs) { bs = s2; bj = kk; }
      }
      conf = bs; cls = bj;
    }
  } else {
    conf = xla_sigmoid(gb);
  }

  if (w == 0) {
    float x1 = __fsub_rn(ax, lt0);
    float y1 = __fsub_rn(ay, lt1);
    float x2 = __fadd_rn(ax, lt2);
    float y2 = __fadd_rn(ay, lt3);
    float cx = __fmul_rn(__fadd_rn(x1, x2), 0.5f);
    float cy = __fmul_rn(__fadd_rn(y1, y2), 0.5f);
    float ww = __fsub_rn(x2, x1);
    float hh = __fsub_rn(y2, y1);
    int t = b * NA_TOT + lvlbase + a0w + idx;
    oboxes[t] = make_float4(__fmul_rn(cx, stridef), __fmul_rn(cy, stridef),
                            __fmul_rn(ww, stridef), __fmul_rn(hh, stridef));
    conf = (conf > CONFTHR) ? conf : 0.0f;
    oconf[t] = conf;
    oclsf[t] = (float)cls;
  }
}

// ---------------------------------------------------------------------------
// Kernel 2a: per-image select (r18-validated verbatim): descent + compact ->
// global keys.
// ---------------------------------------------------------------------------
struct __align__(16) K2Lds {
  unsigned confL[NA_TOT];               // 33600 B
  unsigned hist[16][257];               // 16448 B
  unsigned tot[257];
  unsigned Tarr[257];
};                                      // ~52 KB

__global__ __launch_bounds__(1024) void yolo_select_kernel(
    const float* __restrict__ conf,
    unsigned long long* __restrict__ g_keys, unsigned* __restrict__ g_scnt,
    float* __restrict__ g_rowd, unsigned long long* __restrict__ g_clsMask) {
  __shared__ K2Lds u;
  __shared__ unsigned s_need, s_prefix, s_found, s_B, s_scnt, s_cut, s_done;
  int b    = blockIdx.x;
  int tid  = threadIdx.x;
  int lane = tid & 63;
  int wv   = tid >> 6;
  const unsigned* confu = (const unsigned*)conf + (size_t)b * NA_TOT;
  unsigned long long* gk = g_keys + (size_t)b * GKCAP;

  for (int i = tid; i < NA_TOT; i += 1024) u.confL[i] = confu[i];
  {
    float4 z4 = make_float4(0.f, 0.f, 0.f, 0.f);
    float4* gr = (float4*)(g_rowd + (size_t)b * 1024 * 8);
    for (int k = tid; k < 2048; k += 1024) gr[k] = z4;
  }
  for (int i = tid; i < NCLS * 16; i += 1024)
    g_clsMask[(size_t)b * (NCLS * 16) + i] = 0ull;
  if (tid == 0) { s_need = 1024; s_prefix = 0; s_cut = 0; s_done = 0; s_scnt = 0; }
  __syncthreads();

  for (int lv = 0; lv < 4; ++lv) {
    __syncthreads();
    if (s_done) break;                          // uniform
    for (int i = tid; i < 16 * 257; i += 1024) ((unsigned*)u.hist)[i] = 0;
    if (tid == 0) { s_found = 0; s_B = 0; }
    __syncthreads();
    unsigned pfx = s_prefix;
    for (int it = 0; it < 9; ++it) {
      int i = tid + it * 1024;
      unsigned c = (i < NA_TOT) ? u.confL[i] : 0u;
      bool in; unsigned bin;
      if (lv == 0)      { in = true;                bin = c >> 23; }
      else if (lv == 1) { in = ((c >> 23) == pfx);  bin = (c >> 15) & 0xFF; }
      else if (lv == 2) { in = ((c >> 15) == pfx);  bin = (c >> 7) & 0xFF; }
      else              { in = ((c >> 7)  == pfx);  bin = c & 0x7F; }
      bool act = (c != 0) && in;
      unsigned long long ab = __ballot(act);
      if (ab) {                                 // wave-uniform branch
        int fl = __ffsll(ab) - 1;
        unsigned fbin = __shfl(bin, fl);
        unsigned long long same = __ballot(act && (bin == fbin));
        if (same == ab) {
          if (lane == fl) atomicAdd(&u.hist[wv][fbin], (unsigned)__popcll(ab));
        } else if (act) {
          atomicAdd(&u.hist[wv][bin], 1u);
        }
      }
    }
    __syncthreads();
    if (tid < 256) {
      unsigned s = 0;
      #pragma unroll
      for (int q = 0; q < 16; ++q) s += u.hist[q][tid];
      u.tot[tid] = s;
    }
    __syncthreads();
    if (tid < 64) {
      unsigned carry = 0;
      if (tid == 0) u.Tarr[256] = 0;
      for (int ch = 3; ch >= 0; --ch) {
        int bb = ch * 64 + tid;
        unsigned v = u.tot[bb];
        #pragma unroll
        for (int off = 1; off < 64; off <<= 1) {
          unsigned t2 = __shfl_down(v, off);
          if (tid + off < 64) v += t2;
        }
        u.Tarr[bb] = v + carry;
        carry += __shfl(v, 0);
      }
    }
    __syncthreads();
    unsigned need = s_need;
    if (tid < 256) {
      unsigned h = u.tot[tid];
      if (h > 0 && u.Tarr[tid + 1] < need && u.Tarr[tid + 1] + h >= need) {
        s_B = (unsigned)tid; s_found = 1;
      }
    }
    __syncthreads();
    if (tid == 0) {
      if (!s_found) { s_cut = 1; s_done = 1; }
      else {
        unsigned B = s_B;
        unsigned selcnt = (1024u - need) + u.Tarr[B];
        if (selcnt <= (unsigned)RANKCAP || lv == 3) {
          s_done = 1;
          if (lv == 0)      s_cut = B << 23;
          else if (lv == 1) s_cut = (s_prefix << 23) | (B << 15);
          else if (lv == 2) s_cut = (s_prefix << 15) | (B << 7);
          else              s_cut = (s_prefix << 7)  | B;
        } else {
          s_need   = need - u.Tarr[B + 1];
          s_prefix = (s_prefix << 8) | B;
        }
      }
    }
  }
  __syncthreads();

  unsigned cut = s_cut;
  for (int it = 0; it < 9; ++it) {
    int i = tid + it * 1024;
    unsigned c = (i < NA_TOT) ? u.confL[i] : 0u;
    bool sel = (c != 0 && c >= cut);
    unsigned long long bal = __ballot(sel);
    unsigned base2 = 0;
    if (lane == 0 && bal) base2 = atomicAdd(&s_scnt, (unsigned)__popcll(bal));
    base2 = __shfl(base2, 0);
    if (sel) {
      unsigned p = base2 + (unsigned)__popcll(bal & ((1ull << lane) - 1ull));
      if (p < SSORT)
        gk[p] = ((unsigned long long)c << 32) |
                (unsigned long long)(0xFFFFFFFFu - (unsigned)i);
    }
  }
  __syncthreads();
  if (tid == 0) {
    unsigned sc = s_scnt; if (sc > SSORT) sc = SSORT;
    g_scnt[b] = sc;
    if (sc & 1u) gk[sc] = 0ull;                 // pad for paired reads
  }
}

// ---------------------------------------------------------------------------
// Kernel 2b: rank + scatter, 8 blocks/image, keys staged to own LDS
// (r18-validated verbatim).
// ---------------------------------------------------------------------------
__global__ __launch_bounds__(256) void yolo_rank_kernel(
    const unsigned long long* __restrict__ g_keys,
    const unsigned* __restrict__ g_scnt,
    const float4* __restrict__ boxes, const float* __restrict__ clsf,
    float* __restrict__ g_rowd, unsigned long long* __restrict__ g_clsMask) {
  __shared__ __align__(16) unsigned long long lk[GKCAP];   // 16,448 B
  int bx   = blockIdx.x;
  int b    = bx >> 3;
  int part = bx & 7;
  int tid  = threadIdx.x;
  const unsigned long long* gk = g_keys + (size_t)b * GKCAP;
  unsigned scnt = g_scnt[b];                    // uniform
  unsigned snp  = (scnt + 1u) & ~1u;

  for (unsigned i = tid; i < snp; i += 256) lk[i] = gk[i];   // coalesced
  __syncthreads();

  unsigned e = (unsigned)(part * 256 + tid);
  if (e >= scnt) return;
  unsigned long long mykey = lk[e];
  unsigned r = 0;
  #pragma unroll 4
  for (unsigned j = 0; j < snp; j += 2) {       // LDS b128 broadcast
    ulonglong2 kk = *reinterpret_cast<const ulonglong2*>(&lk[j]);
    r += (kk.x > mykey) ? 1u : 0u;
    r += (kk.y > mykey) ? 1u : 0u;
  }

  if (r < 1024) {                               // == lax.top_k truncation
    unsigned a = 0xFFFFFFFFu - (unsigned)(mykey & 0xFFFFFFFFull);
    float4 cb = boxes[(size_t)b * NA_TOT + a];
    float cls = clsf[(size_t)b * NA_TOT + a];
    float* rowd = g_rowd + (size_t)b * 1024 * 8;
    float4* gr = (float4*)(rowd + (size_t)r * 8);
    gr[0] = cb;
    gr[1] = make_float4(__uint_as_float((unsigned)(mykey >> 32)), cls, 0.f, 0.f);
    atomicOr(&g_clsMask[(size_t)b * (NCLS * 16) + (int)cls * 16 + (r >> 6)],
             1ull << (r & 63));
  }
}

// ---------------------------------------------------------------------------
// Kernel 3: per-image NMS (r12/r18-validated verbatim): parallel row build +
// per-class-parallel walks + parallel popcount emit + sticky tail.
// ---------------------------------------------------------------------------
struct K3Lds {
  unsigned long long rows[1024][16];    // 131072 B, col-swizzled: phys = q^(tid&15)
  float    rowdata[1024][6];            //  24576 B
  unsigned long long am[16];            //    128 B
};                                      // ~155.8 KB

__global__ __launch_bounds__(1024) void yolo_nms_kernel(
    const float* __restrict__ g_rowd,
    const unsigned long long* __restrict__ g_clsMask,
    float* __restrict__ out) {
  __shared__ K3Lds u;
  __shared__ unsigned s_sticky, s_fill;
  int b    = blockIdx.x;
  int tid  = threadIdx.x;
  const unsigned long long* cm = g_clsMask + (size_t)b * (NCLS * 16);

  {
    const float4* gr = (const float4*)(g_rowd + ((size_t)b * 1024 + tid) * 8);
    float4 v0 = gr[0];
    float4 v1 = gr[1];
    u.rowdata[tid][0] = v0.x; u.rowdata[tid][1] = v0.y;
    u.rowdata[tid][2] = v0.z; u.rowdata[tid][3] = v0.w;
    u.rowdata[tid][4] = v1.x; u.rowdata[tid][5] = v1.y;
  }
  {
    unsigned long long* flat = &u.rows[0][0];
    for (int k = tid; k < 1024 * 16; k += 1024) flat[k] = 0ull;
  }
  if (tid < 16) u.am[tid] = 0ull;
  if (tid == 0) { s_sticky = 0xFFFFFFFFu; s_fill = 0; }
  __syncthreads();

  // ---- build suppression-bit rows (same-class pairs; exact IoU sequence) ----
  {
    float cls = u.rowdata[tid][5];
    int c = (int)cls;
    const unsigned long long* cmask = cm + c * 16;
    bool valid = (cmask[tid >> 6] >> (tid & 63)) & 1ull;
    if (valid) {
      float bx0 = u.rowdata[tid][0], by0 = u.rowdata[tid][1];
      float bw0 = u.rowdata[tid][2], bh0 = u.rowdata[tid][3];
      float off = __fmul_rn(cls, 7680.0f);
      float hw  = __fmul_rn(bw0, 0.5f), hh = __fmul_rn(bh0, 0.5f);
      float wx1 = __fadd_rn(__fsub_rn(bx0, hw), off);
      float wy1 = __fadd_rn(__fsub_rn(by0, hh), off);
      float wx2 = __fadd_rn(__fadd_rn(bx0, hw), off);
      float wy2 = __fadd_rn(__fadd_rn(by0, hh), off);
      float a1  = __fmul_rn(__fsub_rn(wx2, wx1), __fsub_rn(wy2, wy1));
      int sw = tid & 15;
      for (int q = 0; q < 16; ++q) {
        unsigned long long m = cmask[q];
        while (m) {
          int bit = __ffsll(m) - 1;
          m &= m - 1ull;
          int j = q * 64 + bit;
          float jx = u.rowdata[j][0], jy = u.rowdata[j][1];
          float jw = u.rowdata[j][2], jh = u.rowdata[j][3];
          float jhw = __fmul_rn(jw, 0.5f), jhh = __fmul_rn(jh, 0.5f);
          float jx1 = __fadd_rn(__fsub_rn(jx, jhw), off);
          float jy1 = __fadd_rn(__fsub_rn(jy, jhh), off);
          float jx2 = __fadd_rn(__fadd_rn(jx, jhw), off);
          float jy2 = __fadd_rn(__fadd_rn(jy, jhh), off);
          float ltx = fmaxf(wx1, jx1), lty = fmaxf(wy1, jy1);
          float rbx = fminf(wx2, jx2), rby = fminf(wy2, jy2);
          float iw = fmaxf(__fsub_rn(rbx, ltx), 0.0f);
          float ih = fmaxf(__fsub_rn(rby, lty), 0.0f);
          float inter = __fmul_rn(iw, ih);
          float a2 = __fmul_rn(__fsub_rn(jx2, jx1), __fsub_rn(jy2, jy1));
          float den = __fadd_rn(__fsub_rn(__fadd_rn(a1, a2), inter), 1e-7f);
          float iou = inter / den;
          if (iou > 0.7f)
            u.rows[tid][(j >> 6) ^ sw] |= (1ull << (j & 63));
        }
      }
    }
  }
  __syncthreads();

  // ---- per-class-parallel walks (80 threads; register alive masks) ----
  if (tid < NCLS) {
    const unsigned long long* cmask = cm + tid * 16;
    unsigned long long alive[16];
    bool any = false;
    #pragma unroll
    for (int q = 0; q < 16; ++q) { alive[q] = cmask[q]; any |= (alive[q] != 0ull); }
    while (any) {
      int r = -1;
      #pragma unroll
      for (int q = 0; q < 16; ++q)
        if (r < 0 && alive[q]) r = q * 64 + (__ffsll(alive[q]) - 1);
      atomicOr(&u.am[r >> 6], 1ull << (r & 63));
      int sw = r & 15;
      unsigned long long selfw = u.rows[r][(r >> 6) ^ sw];
      bool selfbit = (selfw >> (r & 63)) & 1ull;
      if (!selfbit) { atomicMin(&s_sticky, (unsigned)r); break; }  // sticky
      any = false;
      #pragma unroll
      for (int q = 0; q < 16; ++q) {
        alive[q] &= ~u.rows[r][q ^ sw];
        any |= (alive[q] != 0ull);
      }
    }
  }
  __syncthreads();

  // ---- parallel emit: survivor r -> row popc(am below r) ----
  unsigned rs = s_sticky;
  {
    unsigned r = (unsigned)tid;
    bool surv = (u.am[r >> 6] >> (r & 63)) & 1ull;
    if (surv && r <= rs) {
      unsigned e2 = 0;
      int hi = (int)(r >> 6);
      #pragma unroll
      for (int q = 0; q < 16; ++q) {
        unsigned long long m = u.am[q];
        if (q < hi)       e2 += (unsigned)__popcll(m);
        else if (q == hi) e2 += (unsigned)__popcll(m & ((1ull << (r & 63)) - 1ull));
      }
      if (e2 < MAXDET) {
        float* orow = out + (size_t)b * (MAXDET * 6) + (size_t)e2 * 6;
        orow[0] = u.rowdata[r][0];
        orow[1] = u.rowdata[r][1];
        orow[2] = u.rowdata[r][2];
        orow[3] = u.rowdata[r][3];
        orow[4] = u.rowdata[r][4];
        orow[5] = u.rowdata[r][5];
      }
    }
  }
  if (tid == 0) {
    unsigned fill;
    if (rs != 0xFFFFFFFFu) {
      unsigned es = 0;
      int hi = (int)(rs >> 6);
      #pragma unroll
      for (int q = 0; q < 16; ++q) {
        unsigned long long m = u.am[q];
        if (q < hi)       es += (unsigned)__popcll(m);
        else if (q == hi) es += (unsigned)__popcll(m & ((1ull << (rs & 63)) - 1ull));
      }
      fill = es + 1;
    } else {
      unsigned S = 0;
      #pragma unroll
      for (int q = 0; q < 16; ++q) S += (unsigned)__popcll(u.am[q]);
      fill = S;
    }
    s_fill = (fill > (unsigned)MAXDET) ? (unsigned)MAXDET : fill;
  }
  __syncthreads();

  {
    unsigned fill = s_fill;
    bool st = (rs != 0xFFFFFFFFu);
    float* orow = out + (size_t)b * (MAXDET * 6);
    for (int i = (int)fill * 6 + tid; i < MAXDET * 6; i += 1024) {
      float v = 0.0f;
      if (st) v = u.rowdata[rs][i - (i / 6) * 6];
      orow[i] = v;
    }
  }
}

extern "C" void kernel_launch(void* const* d_in, const int* in_sizes, int n_in,
                              void* d_out, int out_size, void* d_ws, size_t ws_size,
                              hipStream_t stream) {
  const float* f0 = (const float*)d_in[0];
  const float* f1 = (const float*)d_in[1];
  const float* f2 = (const float*)d_in[2];
  float* out = (float*)d_out;

  char* ws = (char*)d_ws;
  float4* boxes = (float4*)ws;                                       // 4,300,800
  float*  conf  = (float*)(ws + (size_t)NBATCH * NA_TOT * 16);       // 1,075,200
  float*  clsf  = (float*)(ws + (size_t)NBATCH * NA_TOT * 20);       // 1,075,200
  size_t off = (size_t)NBATCH * NA_TOT * 24;                         // 6,451,200
  float*  rowd  = (float*)(ws + off);                         off += 1048576;
  unsigned long long* clsm  = (unsigned long long*)(ws + off); off += 327680;
  unsigned long long* gkeys = (unsigned long long*)(ws + off); off += (size_t)NBATCH * GKCAP * 8;
  unsigned* scnts = (unsigned*)(ws + off);

  yolo_decode_kernel<<<NBATCH * TILES_PER_IMG, 256, 0, stream>>>(
      f0, f1, f2, boxes, conf, clsf);
  yolo_select_kernel<<<NBATCH, 1024, 0, stream>>>(conf, gkeys, scnts,
                                                  rowd, clsm);
  yolo_rank_kernel<<<NBATCH * 8, 256, 0, stream>>>(gkeys, scnts, boxes, clsf,
                                                   rowd, clsm);
  yolo_nms_kernel<<<NBATCH, 1024, 0, stream>>>(rowd, clsm, out);
}